// Round 7
// baseline (264.153 us; speedup 1.0000x reference)
//
#include <hip/hip_runtime.h>
#include <hip/hip_bf16.h>
#include <float.h>

// Problem constants (B,H,W,D,K) = (16,32,32,256,8192)
#define NROWS 16384
#define DDIM  256
#define KCB   8192
#define ZQ_ELEMS 4194304

// ws layout (~2.2 MB; r0-proven)
#define WS_ESQ_OFF   0                      // float[8192]
#define WS_ZSQ_OFF   32768                  // float[16384]
#define WS_CAND_OFF  98304                  // u32[16384*32] = 2 MB
#define WS_PART_OFF  (98304 + 2097152)      // float[4096]

#define QWINDOW 410   // rescore window: 0.025 in 1/16384 fixed-point quanta

typedef __attribute__((ext_vector_type(8))) short short8;
typedef __attribute__((ext_vector_type(4))) float floatx4;

__device__ __forceinline__ unsigned short bf16_rn(float f) {
    unsigned u = __float_as_uint(f);
    return (unsigned short)((u + 0x7FFFu + ((u >> 16) & 1u)) >> 16);
}

// async global->LDS DMA, 16 B per lane; LDS dest = wave-uniform base + lane*16
__device__ __forceinline__ void gload_lds16(const void* g, void* l) {
    __builtin_amdgcn_global_load_lds(
        (const __attribute__((address_space(1))) void*)(uintptr_t)g,
        (__attribute__((address_space(3))) void*)(unsigned)(uintptr_t)l, 16, 0, 0);
}

// ---------- prep: bf16 convert + numpy-pairwise sumsq (bit-exact, proven r3) ----
__global__ __launch_bounds__(256) void prep_kernel(
    const float* __restrict__ z, const float* __restrict__ cb,
    unsigned short* __restrict__ z16, unsigned short* __restrict__ cb16,
    float* __restrict__ esq, float* __restrict__ zsq) {
#pragma clang fp contract(off)
    int tid = threadIdx.x;
    int rowb = tid >> 2, sub = tid & 3;
    int b = sub >> 1, jq = sub & 1;
    int row = blockIdx.x * 64 + rowb;
    const float* src; unsigned short* dst; float* o;
    if (row < KCB) { src = cb + (size_t)row * DDIM; dst = cb16 + (size_t)row * DDIM; o = esq + row; }
    else { int r = row - KCB; src = z + (size_t)r * DDIM; dst = z16 + (size_t)r * DDIM; o = zsq + r; }
    float r0 = 0.f, r1 = 0.f, r2 = 0.f, r3 = 0.f;
#pragma unroll
    for (int t = 0; t < 16; ++t) {
        int off = b * 128 + t * 8 + jq * 4;
        float4 v = *(const float4*)(src + off);
        float q0 = v.x * v.x, q1 = v.y * v.y, q2 = v.z * v.z, q3 = v.w * v.w;
        r0 = r0 + q0; r1 = r1 + q1; r2 = r2 + q2; r3 = r3 + q3;
        ushort4 w;
        w.x = bf16_rn(v.x); w.y = bf16_rn(v.y); w.z = bf16_rn(v.z); w.w = bf16_rn(v.w);
        *(ushort4*)(dst + off) = w;
    }
    float s = (r0 + r1) + (r2 + r3);
    s = s + __shfl_xor(s, 1);   // jq pair
    s = s + __shfl_xor(s, 2);   // block pair
    if (sub == 0) *o = s;
}

// ---------- bf16 MFMA filter: block = 128 z-rows x 512 cols, 8 waves ----------
// R0/R4/R5/R6 all ~114us: barrier-drain, counted-vmcnt, reg-pipelining, and
// 2x occupancy were each NULL. The invariant across all four: per-CU LDS
// traffic (reads 640KB + DMA-writes 288KB per 64x512 block = 3.8 GB total
// = ~55 B/cyc/CU = ~65% of the 85 B/cyc ds_read_b128 ceiling) — the most
// utilized shared pipe. THIS version attacks LDS bytes/output:
//   128x512 block, wave = full-height 128-row x 64-col panel (wm=1,wn=8):
//   reads = A 64KB x8 waves + B 256KB x1 = 768KB per DOUBLE-size block
//   -> total LDS traffic 3.8 GB -> 2.2 GB (1.7x), DMA inst count halved,
//   prologue/epilogue block count halved.
// B staged as col-full K=32 chunks (32KB, dbuf) in a pair-interleaved
// swizzled layout (2 cols share a 128B row; slot = (4*(col&1)+g) ^ (cp&7)):
// B-frag reads hit each bank-quad exactly 2x (free), A-frag layout unchanged
// (proven). MFMA input bytes and K-ascending accumulation order are
// bit-identical to the proven kernel -> absmax stays 0.
// LDS 136KB -> 1 block/CU, 8 waves (R6: concurrency is not the constraint).
__global__ __launch_bounds__(512, 2) void gemm_filter_kernel(
    const unsigned short* __restrict__ z16, const unsigned short* __restrict__ cb16,
    const float* __restrict__ esq, unsigned* __restrict__ cand) {
    __shared__ unsigned short As[128 * 256];    // 64 KB
    __shared__ unsigned short Bs[2][512 * 32];  // 2 x 32 KB
    __shared__ unsigned st[128][8][2];          // 8 KB cross-wave top-2 merge

    const int tid = threadIdx.x;
    const int w = tid >> 6, lane = tid & 63;    // w = wave's 64-col panel id
    const int c = lane & 15, q = lane >> 4;
    const int m0 = blockIdx.y * 128;
    const int nbase = blockIdx.x * 512;

    // ---- prologue: A tile (8 DMA/wave) + B chunk 0 (4 DMA/wave) ----
#pragma unroll
    for (int p = 0; p < 8; ++p) {
        int s = (w * 8 + p) * 64 + lane;        // 0..4095
        int row = s >> 5, jp = s & 31;          // row 0..127, granule 0..31
        int j = (jp & 24) | ((jp & 7) ^ (row & 7));   // source-addr XOR swizzle
        gload_lds16(z16 + (size_t)(m0 + row) * 256 + j * 8,
                    (char*)As + (w * 8 + p) * 1024);
    }
#pragma unroll
    for (int p = 0; p < 4; ++p) {
        int s = (w * 4 + p) * 64 + lane;        // 0..2047
        int cp = s >> 3, sl = s & 7;            // col-pair 0..255, slot 0..7
        int t = sl ^ (cp & 7);                  // (b,g) stored at this slot
        int bb = t >> 2, g = t & 3;
        gload_lds16(cb16 + (size_t)(nbase + 2 * cp + bb) * 256 + g * 8,
                    (char*)Bs[0] + (w * 4 + p) * 1024);
    }

    floatx4 acc[8][4];   // [f][nf]: row f*16+q*4+r, col w*64+nf*16+c
#pragma unroll
    for (int f = 0; f < 8; ++f)
#pragma unroll
        for (int nf = 0; nf < 4; ++nf) acc[f][nf] = (floatx4){0.f, 0.f, 0.f, 0.f};

    __syncthreads();

#pragma unroll
    for (int kt = 0; kt < 8; ++kt) {            // K-steps of 32
        const int cur = kt & 1;
        if (kt < 7) {   // prefetch next chunk into the other buffer
#pragma unroll
            for (int p = 0; p < 4; ++p) {
                int s = (w * 4 + p) * 64 + lane;
                int cp = s >> 3, sl = s & 7;
                int t = sl ^ (cp & 7);
                int bb = t >> 2, g = t & 3;
                gload_lds16(cb16 + (size_t)(nbase + 2 * cp + bb) * 256 + (kt + 1) * 32 + g * 8,
                            (char*)Bs[cur ^ 1] + (w * 4 + p) * 1024);
            }
        }
        short8 af[8];
#pragma unroll
        for (int f = 0; f < 8; ++f) {
            int row = f * 16 + c;
            int phys = (kt >> 1) * 8 + ((((kt & 1) * 4 + q)) ^ (row & 7));
            af[f] = *(const short8*)((const char*)As + row * 512 + phys * 16);
        }
        short8 bf[4];
#pragma unroll
        for (int nf = 0; nf < 4; ++nf) {
            int col = w * 64 + nf * 16 + c;
            int cp = col >> 1;
            int sl = (4 * (c & 1) + q) ^ (cp & 7);
            bf[nf] = *(const short8*)((const char*)Bs[cur] + cp * 128 + sl * 16);
        }
#pragma unroll
        for (int f = 0; f < 8; ++f)
#pragma unroll
            for (int nf = 0; nf < 4; ++nf)
                acc[f][nf] = __builtin_amdgcn_mfma_f32_16x16x32_bf16(
                    af[f], bf[nf], acc[f][nf], 0, 0, 0);
        __syncthreads();   // buf cur consumed; next chunk's DMA drained here
    }

    // ---- epilogue (once per block): fixed-point pack + top-2 ----
    float ekf[4]; unsigned kb[4];
#pragma unroll
    for (int nf = 0; nf < 4; ++nf) {
        int col = nbase + w * 64 + nf * 16 + c;
        ekf[nf] = (esq[col] + 8.0f) * 16384.0f;   // key+8 in quanta
        kb[nf] = (unsigned)col;
    }
    unsigned b1[8][4], b2[8][4];
#pragma unroll
    for (int f = 0; f < 8; ++f)
#pragma unroll
        for (int r = 0; r < 4; ++r) { b1[f][r] = 0xFFFFFFFFu; b2[f][r] = 0xFFFFFFFFu; }
#pragma unroll
    for (int f = 0; f < 8; ++f)
#pragma unroll
        for (int r = 0; r < 4; ++r)
#pragma unroll
            for (int nf = 0; nf < 4; ++nf) {
                float fx = fmaf(-32768.0f, acc[f][nf][r], ekf[nf]);
                unsigned p = ((unsigned)fx << 13) | kb[nf];
                // top-2 insert: b2 = med3(p,b1,b2); b1 = min(b1,p)
                unsigned nb2;
                asm("v_med3_u32 %0, %1, %2, %3"
                    : "=v"(nb2) : "v"(p), "v"(b1[f][r]), "v"(b2[f][r]));
                b2[f][r] = nb2;
                b1[f][r] = min(b1[f][r], p);
            }
#pragma unroll
    for (int f = 0; f < 8; ++f)
#pragma unroll
        for (int r = 0; r < 4; ++r) {
            unsigned x1 = b1[f][r], x2 = b2[f][r];
#pragma unroll
            for (int sft = 1; sft < 16; sft <<= 1) {
                unsigned o1 = __shfl_xor(x1, sft);
                unsigned o2 = __shfl_xor(x2, sft);
                unsigned mx = max(x1, o1);
                x1 = min(x1, o1);
                x2 = min(min(mx, x2), o2);
            }
            if (c == 0) {
                st[f * 16 + q * 4 + r][w][0] = x1;
                st[f * 16 + q * 4 + r][w][1] = x2;
            }
        }
    __syncthreads();
    if (tid < 128) {
        unsigned a1 = st[tid][0][0], a2 = st[tid][0][1];
#pragma unroll
        for (int ww = 1; ww < 8; ++ww) {
            unsigned p1 = st[tid][ww][0], p2 = st[tid][ww][1];
            unsigned mx = max(a1, p1);
            a1 = min(a1, p1);
            a2 = min(min(mx, a2), p2);
        }
        cand[(size_t)(m0 + tid) * 32 + blockIdx.x * 2 + 0] = a1;
        cand[(size_t)(m0 + tid) * 32 + blockIdx.x * 2 + 1] = a2;
    }
}

// ---------- resolve (numpy-replica fp32 rescore, proven r3/r4) + gather ------
__global__ __launch_bounds__(256) void resolve_gather_kernel(
    const float* __restrict__ z, const float* __restrict__ cb,
    const float* __restrict__ zsq, const float* __restrict__ esq,
    const unsigned* __restrict__ cand, float* __restrict__ out,
    float* __restrict__ partials) {
#pragma clang fp contract(off)
    __shared__ float wls[4];
    int w = threadIdx.x >> 6, l = threadIdx.x & 63;
    int row = blockIdx.x * 4 + w;
    unsigned p = (l < 32) ? cand[(size_t)row * 32 + l] : 0xFFFFFFFFu;
    unsigned m = p;
#pragma unroll
    for (int s = 32; s; s >>= 1) m = min(m, __shfl_xor(m, s));
    bool active = (l < 32) && ((p >> 13) <= (m >> 13) + QWINDOW);
    float dref = FLT_MAX; int k = 0x7FFFFFFF;
    if (active) {
        k = (int)(p & 8191u);
        const float* zr = z + (size_t)row * DDIM;
        const float* er = cb + (size_t)k * DDIM;
        float cacc = 0.f;
#pragma unroll 16
        for (int d = 0; d < DDIM; ++d)
            cacc = fmaf(zr[d], er[d], cacc);   // BLAS-style sequential-K fma chain
        float s1 = zsq[row] + esq[k];          // numpy: z_sq + e_sq (fp32 round)
        float two = 2.0f * cacc;               // exact
        dref = s1 - two;                       // single fp32 round
    }
#pragma unroll
    for (int s = 32; s; s >>= 1) {
        float od = __shfl_xor(dref, s);
        int ok = __shfl_xor(k, s);
        if (od < dref || (od == dref && ok < k)) { dref = od; k = ok; }
    }
    if (l == 0) out[ZQ_ELEMS + row] = (float)k;
    float ls = 0.f;
#pragma unroll
    for (int t = 0; t < 4; ++t) {
        int d = l + t * 64;
        float e = cb[(size_t)k * DDIM + d];
        float zv = z[(size_t)row * DDIM + d];
        out[(size_t)row * DDIM + d] = zv + (e - zv);  // z_q_st == z_q numerically
        float df = zv - e;
        ls = fmaf(df, df, ls);
    }
#pragma unroll
    for (int s = 32; s; s >>= 1) ls += __shfl_xor(ls, s);
    if (l == 0) wls[w] = ls;
    __syncthreads();
    if (threadIdx.x == 0)
        partials[blockIdx.x] = (wls[0] + wls[1]) + (wls[2] + wls[3]);
}

__global__ __launch_bounds__(256) void final_kernel(const float* __restrict__ partials,
                                                    float* __restrict__ out) {
    __shared__ double wd[4];
    int w = threadIdx.x >> 6, l = threadIdx.x & 63;
    double s = 0.0;
#pragma unroll
    for (int j = 0; j < 16; ++j) s += (double)partials[threadIdx.x + j * 256];
#pragma unroll
    for (int sh = 32; sh; sh >>= 1) s += __shfl_xor(s, sh);
    if (l == 0) wd[w] = s;
    __syncthreads();
    if (threadIdx.x == 0)
        out[ZQ_ELEMS + NROWS] =
            (float)(1.25 * ((wd[0] + wd[1]) + (wd[2] + wd[3])) / (double)ZQ_ELEMS);
}

extern "C" void kernel_launch(void* const* d_in, const int* in_sizes, int n_in,
                              void* d_out, int out_size, void* d_ws, size_t ws_size,
                              hipStream_t stream) {
    const float* z = (const float*)d_in[0];
    const float* cb = (const float*)d_in[1];
    float* out = (float*)d_out;
    char* ws = (char*)d_ws;
    float* esq = (float*)(ws + WS_ESQ_OFF);
    float* zsq = (float*)(ws + WS_ZSQ_OFF);
    unsigned* cand = (unsigned*)(ws + WS_CAND_OFF);
    float* partials = (float*)(ws + WS_PART_OFF);
    // bf16 scratch inside d_out (12 MB < 16.8 MB); overwritten by outputs later
    unsigned short* z16 = (unsigned short*)d_out;
    unsigned short* cb16 = z16 + (size_t)NROWS * DDIM;

    prep_kernel<<<dim3((KCB + NROWS) / 64), 256, 0, stream>>>(z, cb, z16, cb16, esq, zsq);
    gemm_filter_kernel<<<dim3(16, NROWS / 128), 512, 0, stream>>>(z16, cb16, esq, cand);
    resolve_gather_kernel<<<dim3(NROWS / 4), 256, 0, stream>>>(z, cb, zsq, esq, cand, out, partials);
    final_kernel<<<1, 256, 0, stream>>>(partials, out);
}

// Round 8
// 237.496 us; speedup vs baseline: 1.1122x; 1.1122x over previous
//
#include <hip/hip_runtime.h>
#include <hip/hip_bf16.h>
#include <float.h>

// Problem constants (B,H,W,D,K) = (16,32,32,256,8192)
#define NROWS 16384
#define DDIM  256
#define KCB   8192
#define ZQ_ELEMS 4194304

// ws layout (~2.2 MB; r0-proven)
#define WS_ESQ_OFF   0                      // float[8192]
#define WS_ZSQ_OFF   32768                  // float[16384]
#define WS_CAND_OFF  98304                  // u32[16384*32] = 2 MB
#define WS_PART_OFF  (98304 + 2097152)      // float[4096]

#define QWINDOW 410   // rescore window: 0.025 in 1/16384 fixed-point quanta

typedef __attribute__((ext_vector_type(8))) short short8;
typedef __attribute__((ext_vector_type(4))) float floatx4;

__device__ __forceinline__ unsigned short bf16_rn(float f) {
    unsigned u = __float_as_uint(f);
    return (unsigned short)((u + 0x7FFFu + ((u >> 16) & 1u)) >> 16);
}

// async global->LDS DMA, 16 B per lane; LDS dest = wave-uniform base + lane*16
__device__ __forceinline__ void gload_lds16(const void* g, void* l) {
    __builtin_amdgcn_global_load_lds(
        (const __attribute__((address_space(1))) void*)(uintptr_t)g,
        (__attribute__((address_space(3))) void*)(unsigned)(uintptr_t)l, 16, 0, 0);
}

// ---------- prep: bf16 convert + numpy-pairwise sumsq (bit-exact, proven r3) ----
__global__ __launch_bounds__(256) void prep_kernel(
    const float* __restrict__ z, const float* __restrict__ cb,
    unsigned short* __restrict__ z16, unsigned short* __restrict__ cb16,
    float* __restrict__ esq, float* __restrict__ zsq) {
#pragma clang fp contract(off)
    int tid = threadIdx.x;
    int rowb = tid >> 2, sub = tid & 3;
    int b = sub >> 1, jq = sub & 1;
    int row = blockIdx.x * 64 + rowb;
    const float* src; unsigned short* dst; float* o;
    if (row < KCB) { src = cb + (size_t)row * DDIM; dst = cb16 + (size_t)row * DDIM; o = esq + row; }
    else { int r = row - KCB; src = z + (size_t)r * DDIM; dst = z16 + (size_t)r * DDIM; o = zsq + r; }
    float r0 = 0.f, r1 = 0.f, r2 = 0.f, r3 = 0.f;
#pragma unroll
    for (int t = 0; t < 16; ++t) {
        int off = b * 128 + t * 8 + jq * 4;
        float4 v = *(const float4*)(src + off);
        float q0 = v.x * v.x, q1 = v.y * v.y, q2 = v.z * v.z, q3 = v.w * v.w;
        r0 = r0 + q0; r1 = r1 + q1; r2 = r2 + q2; r3 = r3 + q3;
        ushort4 w;
        w.x = bf16_rn(v.x); w.y = bf16_rn(v.y); w.z = bf16_rn(v.z); w.w = bf16_rn(v.w);
        *(ushort4*)(dst + off) = w;
    }
    float s = (r0 + r1) + (r2 + r3);
    s = s + __shfl_xor(s, 1);   // jq pair
    s = s + __shfl_xor(s, 2);   // block pair
    if (sub == 0) *o = s;
}

// ---------- bf16 MFMA filter: block = 64 z-rows x 512 cols, 8 waves ----------
// R6 structure (best: 113.2us, absmax 0) + XCD-AWARE BLOCK SWIZZLE.
// Falsified so far at the ~114us invariant: barrier drain (R4), counted
// vmcnt (R4), reg pipelining (R5), 2x occupancy (R6), LDS bytes (R7).
// No pipe saturated (MFMA 26 / VALU 38 / LDS ~45 / HBM 5%). Remaining
// shared, config-invariant resource: L3. cb16 = 4.19 MB, just OVER one
// XCD's 4 MiB L2; default x-fastest dispatch round-robins col-panels over
// XCDs -> every XCD's working set ~4.2MB -> B streams from L3 every step:
// 4096 blocks x 256KB = 1.07 GB / 114us = 9.3 TB/s ~ L3 ceiling.
// FIX: bijective remap (nwg=4096 % 8 == 0): xcd = flat&7 owns col-panels
// {2*xcd, 2*xcd+1} x all 256 row-blocks -> per-XCD B working set 512 KB ->
// L2-resident; L3 B-traffic drops ~128x. Compute/layout/epilogue unchanged.
__global__ __launch_bounds__(512, 4) void gemm_filter_kernel(
    const unsigned short* __restrict__ z16, const unsigned short* __restrict__ cb16,
    const float* __restrict__ esq, unsigned* __restrict__ cand) {
    __shared__ unsigned short As[64 * 256];     // 32 KB
    __shared__ unsigned short Bs[2][128 * 64];  // 2 x 16 KB
    __shared__ unsigned st[64][4][2];           // 2 KB cross-wave top-2 merge

    // ---- XCD-aware bijective block swizzle (T1, m204-form) ----
    const unsigned flat = blockIdx.x + gridDim.x * blockIdx.y;  // dispatch order, x fastest
    const unsigned xcd = flat & 7u;
    const unsigned idx = (xcd << 9) + (flat >> 3);   // xcd*512 + flat/8, bijective
    const int bx = (int)(idx >> 8);                  // col-panel 0..15 (2 per XCD)
    const int by = (int)(idx & 255u);                // row-block 0..255

    const int tid = threadIdx.x;
    const int w = tid >> 6, lane = tid & 63;
    const int wm = w >> 2, wn = w & 3;          // wave tile: rows wm*32+, cols wn*32 per chunk
    const int c = lane & 15, q = lane >> 4;
    const int m0 = by * 64;
    const int nbase = bx * 512;

    // prologue: A tile (4 DMA ops/wave) + B chunk 0 (2 ops/wave)
#pragma unroll
    for (int p = 0; p < 4; ++p) {
        int s = (w * 4 + p) * 64 + lane;
        int row = s >> 5, jp = s & 31;
        int j = (jp & 24) | ((jp & 7) ^ (row & 7));   // source-addr XOR swizzle
        gload_lds16(z16 + (size_t)(m0 + row) * 256 + j * 8,
                    (char*)As + (w * 4 + p) * 1024);
    }
#pragma unroll
    for (int p = 0; p < 2; ++p) {
        int s = (w * 2 + p) * 64 + lane;
        int col = s >> 3, jp = s & 7;
        int j = jp ^ (col & 7);
        gload_lds16(cb16 + (size_t)(nbase + col) * 256 + j * 8,
                    (char*)Bs[0] + (w * 2 + p) * 1024);
    }
    __syncthreads();

    floatx4 acc[4][2][2];   // [ct][f][nf] — 64 regs
#pragma unroll
    for (int ct = 0; ct < 4; ++ct)
#pragma unroll
        for (int f = 0; f < 2; ++f)
#pragma unroll
            for (int nf = 0; nf < 2; ++nf) acc[ct][f][nf] = (floatx4){0.f, 0.f, 0.f, 0.f};

    short8 af[2][2];   // [f][ks] for current kt

#pragma unroll
    for (int s5 = 0; s5 < 16; ++s5) {
        const int kt = s5 >> 2, ct = s5 & 3, cur = s5 & 1;
        if (s5 < 15) {   // prefetch next cb chunk into other buffer
            const int nkt = (s5 + 1) >> 2, nct = (s5 + 1) & 3;
#pragma unroll
            for (int p = 0; p < 2; ++p) {
                int s = (w * 2 + p) * 64 + lane;
                int col = s >> 3, jp = s & 7;
                int j = jp ^ (col & 7);
                gload_lds16(cb16 + (size_t)(nbase + nct * 128 + col) * 256 + nkt * 64 + j * 8,
                            (char*)Bs[cur ^ 1] + (w * 2 + p) * 1024);
            }
        }
        if (ct == 0) {   // A-frags for this kt (reused across 4 ct)
#pragma unroll
            for (int f = 0; f < 2; ++f)
#pragma unroll
                for (int ks = 0; ks < 2; ++ks) {
                    int row = wm * 32 + f * 16 + c;
                    af[f][ks] = *(const short8*)((const char*)As + row * 512 +
                                 (kt * 8 + (((ks * 4 + q)) ^ (row & 7))) * 16);
                }
        }
        short8 bf[2][2];
#pragma unroll
        for (int nf = 0; nf < 2; ++nf)
#pragma unroll
            for (int ks = 0; ks < 2; ++ks) {
                int col = wn * 32 + nf * 16 + c;
                bf[nf][ks] = *(const short8*)((const char*)Bs[cur] + col * 128 +
                              (((ks * 4 + q) ^ (col & 7))) * 16);
            }
#pragma unroll
        for (int f = 0; f < 2; ++f)
#pragma unroll
            for (int nf = 0; nf < 2; ++nf) {
                acc[ct][f][nf] = __builtin_amdgcn_mfma_f32_16x16x32_bf16(
                    af[f][0], bf[nf][0], acc[ct][f][nf], 0, 0, 0);
                acc[ct][f][nf] = __builtin_amdgcn_mfma_f32_16x16x32_bf16(
                    af[f][1], bf[nf][1], acc[ct][f][nf], 0, 0, 0);
            }
        __syncthreads();   // buf cur consumed; next chunk's DMA drained here
    }

    // ---- epilogue (once per block): fixed-point pack + top-2 ----
    float ekf[4][2]; unsigned kb[4][2];
#pragma unroll
    for (int ct = 0; ct < 4; ++ct)
#pragma unroll
        for (int nf = 0; nf < 2; ++nf) {
            int col = nbase + ct * 128 + wn * 32 + nf * 16 + c;
            ekf[ct][nf] = (esq[col] + 8.0f) * 16384.0f;   // key+8 in quanta
            kb[ct][nf] = (unsigned)col;
        }
    unsigned b1[2][4], b2[2][4];
#pragma unroll
    for (int f = 0; f < 2; ++f)
#pragma unroll
        for (int r = 0; r < 4; ++r) { b1[f][r] = 0xFFFFFFFFu; b2[f][r] = 0xFFFFFFFFu; }
#pragma unroll
    for (int f = 0; f < 2; ++f)
#pragma unroll
        for (int r = 0; r < 4; ++r)
#pragma unroll
            for (int ct = 0; ct < 4; ++ct)
#pragma unroll
                for (int nf = 0; nf < 2; ++nf) {
                    float fx = fmaf(-32768.0f, acc[ct][f][nf][r], ekf[ct][nf]);
                    unsigned p = ((unsigned)fx << 13) | kb[ct][nf];
                    // top-2 insert: b2 = med3(p,b1,b2); b1 = min(b1,p)
                    unsigned nb2;
                    asm("v_med3_u32 %0, %1, %2, %3"
                        : "=v"(nb2) : "v"(p), "v"(b1[f][r]), "v"(b2[f][r]));
                    b2[f][r] = nb2;
                    b1[f][r] = min(b1[f][r], p);
                }
#pragma unroll
    for (int f = 0; f < 2; ++f)
#pragma unroll
        for (int r = 0; r < 4; ++r) {
            unsigned x1 = b1[f][r], x2 = b2[f][r];
#pragma unroll
            for (int sft = 1; sft < 16; sft <<= 1) {
                unsigned o1 = __shfl_xor(x1, sft);
                unsigned o2 = __shfl_xor(x2, sft);
                unsigned mx = max(x1, o1);
                x1 = min(x1, o1);
                x2 = min(min(mx, x2), o2);
            }
            if (c == 0) {
                st[wm * 32 + f * 16 + q * 4 + r][wn][0] = x1;
                st[wm * 32 + f * 16 + q * 4 + r][wn][1] = x2;
            }
        }
    __syncthreads();
    if (tid < 64) {
        unsigned a1 = st[tid][0][0], a2 = st[tid][0][1];
#pragma unroll
        for (int ww = 1; ww < 4; ++ww) {
            unsigned p1 = st[tid][ww][0], p2 = st[tid][ww][1];
            unsigned mx = max(a1, p1);
            a1 = min(a1, p1);
            a2 = min(min(mx, a2), p2);
        }
        cand[(size_t)(m0 + tid) * 32 + bx * 2 + 0] = a1;
        cand[(size_t)(m0 + tid) * 32 + bx * 2 + 1] = a2;
    }
}

// ---------- resolve (numpy-replica fp32 rescore, proven r3/r4) + gather ------
__global__ __launch_bounds__(256) void resolve_gather_kernel(
    const float* __restrict__ z, const float* __restrict__ cb,
    const float* __restrict__ zsq, const float* __restrict__ esq,
    const unsigned* __restrict__ cand, float* __restrict__ out,
    float* __restrict__ partials) {
#pragma clang fp contract(off)
    __shared__ float wls[4];
    int w = threadIdx.x >> 6, l = threadIdx.x & 63;
    int row = blockIdx.x * 4 + w;
    unsigned p = (l < 32) ? cand[(size_t)row * 32 + l] : 0xFFFFFFFFu;
    unsigned m = p;
#pragma unroll
    for (int s = 32; s; s >>= 1) m = min(m, __shfl_xor(m, s));
    bool active = (l < 32) && ((p >> 13) <= (m >> 13) + QWINDOW);
    float dref = FLT_MAX; int k = 0x7FFFFFFF;
    if (active) {
        k = (int)(p & 8191u);
        const float* zr = z + (size_t)row * DDIM;
        const float* er = cb + (size_t)k * DDIM;
        float cacc = 0.f;
        // float4 loads; fmaf chain sequence and order IDENTICAL to scalar loop
#pragma unroll 8
        for (int d = 0; d < DDIM; d += 4) {
            float4 zv = *(const float4*)(zr + d);
            float4 ev = *(const float4*)(er + d);
            cacc = fmaf(zv.x, ev.x, cacc);
            cacc = fmaf(zv.y, ev.y, cacc);
            cacc = fmaf(zv.z, ev.z, cacc);
            cacc = fmaf(zv.w, ev.w, cacc);
        }
        float s1 = zsq[row] + esq[k];          // numpy: z_sq + e_sq (fp32 round)
        float two = 2.0f * cacc;               // exact
        dref = s1 - two;                       // single fp32 round
    }
#pragma unroll
    for (int s = 32; s; s >>= 1) {
        float od = __shfl_xor(dref, s);
        int ok = __shfl_xor(k, s);
        if (od < dref || (od == dref && ok < k)) { dref = od; k = ok; }
    }
    if (l == 0) out[ZQ_ELEMS + row] = (float)k;
    float ls = 0.f;
#pragma unroll
    for (int t = 0; t < 4; ++t) {
        int d = l + t * 64;
        float e = cb[(size_t)k * DDIM + d];
        float zv = z[(size_t)row * DDIM + d];
        out[(size_t)row * DDIM + d] = zv + (e - zv);  // z_q_st == z_q numerically
        float df = zv - e;
        ls = fmaf(df, df, ls);
    }
#pragma unroll
    for (int s = 32; s; s >>= 1) ls += __shfl_xor(ls, s);
    if (l == 0) wls[w] = ls;
    __syncthreads();
    if (threadIdx.x == 0)
        partials[blockIdx.x] = (wls[0] + wls[1]) + (wls[2] + wls[3]);
}

__global__ __launch_bounds__(256) void final_kernel(const float* __restrict__ partials,
                                                    float* __restrict__ out) {
    __shared__ double wd[4];
    int w = threadIdx.x >> 6, l = threadIdx.x & 63;
    double s = 0.0;
#pragma unroll
    for (int j = 0; j < 16; ++j) s += (double)partials[threadIdx.x + j * 256];
#pragma unroll
    for (int sh = 32; sh; sh >>= 1) s += __shfl_xor(s, sh);
    if (l == 0) wd[w] = s;
    __syncthreads();
    if (threadIdx.x == 0)
        out[ZQ_ELEMS + NROWS] =
            (float)(1.25 * ((wd[0] + wd[1]) + (wd[2] + wd[3])) / (double)ZQ_ELEMS);
}

extern "C" void kernel_launch(void* const* d_in, const int* in_sizes, int n_in,
                              void* d_out, int out_size, void* d_ws, size_t ws_size,
                              hipStream_t stream) {
    const float* z = (const float*)d_in[0];
    const float* cb = (const float*)d_in[1];
    float* out = (float*)d_out;
    char* ws = (char*)d_ws;
    float* esq = (float*)(ws + WS_ESQ_OFF);
    float* zsq = (float*)(ws + WS_ZSQ_OFF);
    unsigned* cand = (unsigned*)(ws + WS_CAND_OFF);
    float* partials = (float*)(ws + WS_PART_OFF);
    // bf16 scratch inside d_out (12 MB < 16.8 MB); overwritten by outputs later
    unsigned short* z16 = (unsigned short*)d_out;
    unsigned short* cb16 = z16 + (size_t)NROWS * DDIM;

    prep_kernel<<<dim3((KCB + NROWS) / 64), 256, 0, stream>>>(z, cb, z16, cb16, esq, zsq);
    gemm_filter_kernel<<<dim3(16, NROWS / 64), 512, 0, stream>>>(z16, cb16, esq, cand);
    resolve_gather_kernel<<<dim3(NROWS / 4), 256, 0, stream>>>(z, cb, zsq, esq, cand, out, partials);
    final_kernel<<<1, 256, 0, stream>>>(partials, out);
}